// Round 1
// baseline (221.281 us; speedup 1.0000x reference)
//
#include <hip/hip_runtime.h>
#include <cstdint>
#include <cstddef>

#define B_   256
#define D_   2048
#define U_   2048
#define NTOT 8192   // 4*U
#define BN   64
#define BK   32
#define KC   1024   // K chunk per ks (Ksplit=4 over K=4096)

typedef _Float16 half8 __attribute__((ext_vector_type(8)));
typedef float floatx16 __attribute__((ext_vector_type(16)));

// ---------------------------------------------------------------------------
// prep: split [x|h] fp32 -> f16 hi/lo, chunk-major layout [chunk=k/8][row][8]
// so GEMM can stage A with contiguous global_load_lds and read fragments
// conflict-free.
// ---------------------------------------------------------------------------
__global__ __launch_bounds__(256) void prep_kernel(
    const float* __restrict__ x, const float* __restrict__ h,
    _Float16* __restrict__ Ahi, _Float16* __restrict__ Alo)
{
    int gid   = blockIdx.x * 256 + threadIdx.x;   // 131072 total
    int chunk = gid >> 8;                         // 0..511
    int row   = gid & 255;                        // 0..255
    int col0  = chunk * 8;                        // global k
    const float* src = (col0 < D_) ? (x + row * D_ + col0)
                                   : (h + row * U_ + (col0 - D_));
    float4 v0 = *(const float4*)(src);
    float4 v1 = *(const float4*)(src + 4);
    float v[8] = {v0.x, v0.y, v0.z, v0.w, v1.x, v1.y, v1.z, v1.w};
    half8 hi, lo;
#pragma unroll
    for (int i = 0; i < 8; ++i) {
        _Float16 hv = (_Float16)v[i];
        hi[i] = hv;
        lo[i] = (_Float16)(v[i] - (float)hv);
    }
    int off = (chunk * 256 + row) * 8;
    *(half8*)(Ahi + off) = hi;   // coalesced 16B stores
    *(half8*)(Alo + off) = lo;
}

// ---------------------------------------------------------------------------
// GEMM: pre_partial[ks][m][n] = A(ks-chunk) @ Wsel columns [c0, c0+64)
// grid = (128 n-tiles, 4 k-splits), 256 threads (4 waves), wave-tile 64x64.
// f16 hi/lo split, 3 MFMA products per tile -> ~fp32 accuracy.
// ---------------------------------------------------------------------------
__global__ __launch_bounds__(256) void gemm_kernel(
    const _Float16* __restrict__ Ahi, const _Float16* __restrict__ Alo,
    const float* __restrict__ Wz, const float* __restrict__ Wi,
    const float* __restrict__ Wf, const float* __restrict__ Wo,
    const float* __restrict__ Uz, const float* __restrict__ Ui,
    const float* __restrict__ Uf, const float* __restrict__ Uo,
    float* __restrict__ P)
{
    __shared__ __align__(16) _Float16 sAhi[4 * 256 * 8];  // 16 KB, chunk-major
    __shared__ __align__(16) _Float16 sAlo[4 * 256 * 8];  // 16 KB
    __shared__ __align__(16) _Float16 sBhi[64 * 40];      // [n][k] padded 32->40
    __shared__ __align__(16) _Float16 sBlo[64 * 40];

    const int t    = threadIdx.x;
    const int w    = t >> 6;          // wave 0..3
    const int lane = t & 63;
    const int nblk = blockIdx.x;      // 0..127
    const int ks   = blockIdx.y;      // 0..3
    const int n0   = nblk * BN;
    const int g    = n0 >> 11;        // gate 0..3
    const int c0   = n0 & (U_ - 1);   // column within gate matrix
    const int krow0  = (ks & 1) * KC; // row offset inside the weight matrix
    const int chunk0 = ks * (KC / 8); // A chunk base

    const float* wa = (g == 0) ? Wz : (g == 1) ? Wi : (g == 2) ? Wf : Wo;
    const float* ua = (g == 0) ? Uz : (g == 1) ? Ui : (g == 2) ? Uf : Uo;
    const float* Bm = (ks < 2) ? wa : ua;

    floatx16 acc[2][2] = {};

    const int lg = lane >> 5;   // 0/1 : k-group within fragment
    const int lm = lane & 31;

    for (int kk = 0; kk < KC / BK; ++kk) {   // 32 iterations
        // ---- stage A tile (256 rows x 32 k), hi+lo, via async DMA ----
        {
            int gch = chunk0 + kk * 4;
#pragma unroll
            for (int i = 0; i < 4; ++i) {
                int gidx = ((gch + i) * 256 + t) * 8;
                int lidx = (i * 256 + t) * 8;
                __builtin_amdgcn_global_load_lds(
                    (const __attribute__((address_space(1))) void*)(Ahi + gidx),
                    (__attribute__((address_space(3))) void*)(sAhi + lidx),
                    16, 0, 0);
                __builtin_amdgcn_global_load_lds(
                    (const __attribute__((address_space(1))) void*)(Alo + gidx),
                    (__attribute__((address_space(3))) void*)(sAlo + lidx),
                    16, 0, 0);
            }
        }
        // ---- load B column-slices (coalesced across lanes), convert, store
        //      transposed [n][k] so fragments are single ds_read_b128 ----
        {
            int n = lane;
            const float* bp = Bm + (size_t)(krow0 + kk * BK + w * 8) * U_ + (c0 + n);
            half8 bhi, blo;
#pragma unroll
            for (int j = 0; j < 8; ++j) {
                float v = bp[(size_t)j * U_];
                _Float16 hv = (_Float16)v;
                bhi[j] = hv;
                blo[j] = (_Float16)(v - (float)hv);
            }
            *(half8*)(&sBhi[n * 40 + w * 8]) = bhi;
            *(half8*)(&sBlo[n * 40 + w * 8]) = blo;
        }
        __syncthreads();
        // ---- compute: 2 m-tiles x 2 n-tiles x 2 k-subs x 3 products ----
#pragma unroll
        for (int ksub = 0; ksub < 2; ++ksub) {
            half8 ah[2], al[2], bh[2], bl[2];
#pragma unroll
            for (int mt = 0; mt < 2; ++mt) {
                int row   = w * 64 + mt * 32 + lm;
                int chunk = ksub * 2 + lg;
                int off   = (chunk * 256 + row) * 8;
                ah[mt] = *(const half8*)(sAhi + off);
                al[mt] = *(const half8*)(sAlo + off);
            }
#pragma unroll
            for (int nt = 0; nt < 2; ++nt) {
                int n   = nt * 32 + lm;
                int off = n * 40 + ksub * 16 + lg * 8;
                bh[nt] = *(const half8*)(sBhi + off);
                bl[nt] = *(const half8*)(sBlo + off);
            }
#pragma unroll
            for (int mt = 0; mt < 2; ++mt)
#pragma unroll
                for (int nt = 0; nt < 2; ++nt) {
                    acc[mt][nt] = __builtin_amdgcn_mfma_f32_32x32x16_f16(
                        ah[mt], bh[nt], acc[mt][nt], 0, 0, 0);
                    acc[mt][nt] = __builtin_amdgcn_mfma_f32_32x32x16_f16(
                        ah[mt], bl[nt], acc[mt][nt], 0, 0, 0);
                    acc[mt][nt] = __builtin_amdgcn_mfma_f32_32x32x16_f16(
                        al[mt], bh[nt], acc[mt][nt], 0, 0, 0);
                }
        }
        __syncthreads();
    }

    // ---- write partials: C/D layout col=lane&31, row=(r&3)+8*(r>>2)+4*(lane>>5)
    float* Pks = P + (size_t)ks * ((size_t)B_ * NTOT);
#pragma unroll
    for (int mt = 0; mt < 2; ++mt)
#pragma unroll
        for (int nt = 0; nt < 2; ++nt) {
            int n = n0 + nt * 32 + lm;
#pragma unroll
            for (int r = 0; r < 16; ++r) {
                int m = w * 64 + mt * 32 + 4 * lg + (r & 3) + 8 * (r >> 2);
                Pks[(size_t)m * NTOT + n] = acc[mt][nt][r];
            }
        }
}

// ---------------------------------------------------------------------------
// gates: reduce 4 partials, add bias, sLSTM exponential-gate math, write
// out = stack([h_t, c_t, n_t, m_t])
// ---------------------------------------------------------------------------
__global__ __launch_bounds__(256) void gates_kernel(
    const float* __restrict__ P,
    const float* __restrict__ c_prev, const float* __restrict__ n_prev,
    const float* __restrict__ m_prev,
    const float* __restrict__ bz, const float* __restrict__ bi,
    const float* __restrict__ bf, const float* __restrict__ bo,
    float* __restrict__ out)
{
    const size_t PS = (size_t)B_ * NTOT;
    const int OS = B_ * U_;
    int gid = blockIdx.x * 256 + threadIdx.x;   // 131072
    int m = gid >> 9;
    int u = (gid & 511) * 4;

    float pre[4][4];
#pragma unroll
    for (int gi = 0; gi < 4; ++gi) {
        const float* base = P + (size_t)m * NTOT + gi * U_ + u;
        float4 s0 = *(const float4*)(base);
        float4 s1 = *(const float4*)(base + PS);
        float4 s2 = *(const float4*)(base + 2 * PS);
        float4 s3 = *(const float4*)(base + 3 * PS);
        pre[gi][0] = s0.x + s1.x + s2.x + s3.x;
        pre[gi][1] = s0.y + s1.y + s2.y + s3.y;
        pre[gi][2] = s0.z + s1.z + s2.z + s3.z;
        pre[gi][3] = s0.w + s1.w + s2.w + s3.w;
    }
    float4 bzv = *(const float4*)(bz + u);
    float4 biv = *(const float4*)(bi + u);
    float4 bfv = *(const float4*)(bf + u);
    float4 bov = *(const float4*)(bo + u);
    float bza[4] = {bzv.x, bzv.y, bzv.z, bzv.w};
    float bia[4] = {biv.x, biv.y, biv.z, biv.w};
    float bfa[4] = {bfv.x, bfv.y, bfv.z, bfv.w};
    float boa[4] = {bov.x, bov.y, bov.z, bov.w};

    float4 cp4 = *(const float4*)(c_prev + m * U_ + u);
    float4 np4 = *(const float4*)(n_prev + m * U_ + u);
    float4 mp4 = *(const float4*)(m_prev + m * U_ + u);
    float cpa[4] = {cp4.x, cp4.y, cp4.z, cp4.w};
    float npa[4] = {np4.x, np4.y, np4.z, np4.w};
    float mpa[4] = {mp4.x, mp4.y, mp4.z, mp4.w};

    float hr[4], cr[4], nr[4], mr[4];
#pragma unroll
    for (int e = 0; e < 4; ++e) {
        float zt = pre[0][e] + bza[e];
        float it = pre[1][e] + bia[e];
        float ft = pre[2][e] + bfa[e];
        float ot = pre[3][e] + boa[e];
        float mp = mpa[e];
        float m_t = fmaxf(it + mp, it);
        float i_t = expf(it - m_t);
        float f_t = expf(ft + mp - m_t);
        float o_t = 1.0f / (1.0f + expf(-ot));
        float z_t = tanhf(zt);
        float c_t = f_t * cpa[e] + i_t * z_t;
        float n_t = f_t * npa[e] + i_t;
        float h_t = o_t * (c_t / (n_t + 1e-8f));
        hr[e] = h_t; cr[e] = c_t; nr[e] = n_t; mr[e] = m_t;
    }
    float4 hv = {hr[0], hr[1], hr[2], hr[3]};
    float4 cv = {cr[0], cr[1], cr[2], cr[3]};
    float4 nv = {nr[0], nr[1], nr[2], nr[3]};
    float4 mv = {mr[0], mr[1], mr[2], mr[3]};
    *(float4*)(out + 0 * OS + m * U_ + u) = hv;
    *(float4*)(out + 1 * OS + m * U_ + u) = cv;
    *(float4*)(out + 2 * OS + m * U_ + u) = nv;
    *(float4*)(out + 3 * OS + m * U_ + u) = mv;
}

extern "C" void kernel_launch(void* const* d_in, const int* in_sizes, int n_in,
                              void* d_out, int out_size, void* d_ws, size_t ws_size,
                              hipStream_t stream)
{
    const float* x  = (const float*)d_in[0];
    const float* h  = (const float*)d_in[1];
    const float* cp = (const float*)d_in[2];
    const float* np = (const float*)d_in[3];
    const float* mp = (const float*)d_in[4];
    const float* Wz = (const float*)d_in[5];
    const float* Wi = (const float*)d_in[6];
    const float* Wf = (const float*)d_in[7];
    const float* Wo = (const float*)d_in[8];
    const float* bz = (const float*)d_in[9];
    const float* bi = (const float*)d_in[10];
    const float* bf = (const float*)d_in[11];
    const float* bo = (const float*)d_in[12];
    const float* Uz = (const float*)d_in[13];
    const float* Ui = (const float*)d_in[14];
    const float* Uf = (const float*)d_in[15];
    const float* Uo = (const float*)d_in[16];

    float* P = (float*)d_ws;                                  // 4*256*8192 f32 = 33.55 MB
    _Float16* Ahi = (_Float16*)((char*)d_ws + (size_t)4 * B_ * NTOT * sizeof(float));
    _Float16* Alo = Ahi + (size_t)B_ * (D_ + U_);             // +2 MB each

    prep_kernel<<<512, 256, 0, stream>>>(x, h, Ahi, Alo);
    gemm_kernel<<<dim3(128, 4), 256, 0, stream>>>(Ahi, Alo,
        Wz, Wi, Wf, Wo, Uz, Ui, Uf, Uo, P);
    gates_kernel<<<512, 256, 0, stream>>>(P, cp, np, mp, bz, bi, bf, bo,
        (float*)d_out);
}

// Round 2
// 210.707 us; speedup vs baseline: 1.0502x; 1.0502x over previous
//
#include <hip/hip_runtime.h>
#include <cstdint>
#include <cstddef>

#define B_   256
#define D_   2048
#define U_   2048
#define NTOT 8192    // 4*U
#define BN   32
#define BK   64
#define KC   2048    // K per ksplit (ksplit=2 over K=4096)
#define ITERS (KC / BK)   // 32

typedef _Float16 half8 __attribute__((ext_vector_type(8)));
typedef float floatx16 __attribute__((ext_vector_type(16)));

// ---------------------------------------------------------------------------
// prep: [x|h] fp32 -> f16 (hi only), chunk-major layout [chunk=k/8][row][8]
// so GEMM stages A with contiguous global_load_lds and reads fragments as
// single ds_read_b128.  Single-product f16 error budget: pre-act err ~3e-3
// -> output err ~100 << threshold 967.
// ---------------------------------------------------------------------------
__global__ __launch_bounds__(256) void prep_kernel(
    const float* __restrict__ x, const float* __restrict__ h,
    _Float16* __restrict__ Ahi)
{
    int gid   = blockIdx.x * 256 + threadIdx.x;   // 131072 total
    int chunk = gid >> 8;                         // 0..511
    int row   = gid & 255;                        // 0..255
    int col0  = chunk * 8;
    const float* src = (col0 < D_) ? (x + row * D_ + col0)
                                   : (h + row * U_ + (col0 - D_));
    float4 v0 = *(const float4*)(src);
    float4 v1 = *(const float4*)(src + 4);
    float v[8] = {v0.x, v0.y, v0.z, v0.w, v1.x, v1.y, v1.z, v1.w};
    half8 hi;
#pragma unroll
    for (int i = 0; i < 8; ++i) hi[i] = (_Float16)v[i];
    *(half8*)(Ahi + (chunk * 256 + row) * 8) = hi;
}

// ---------------------------------------------------------------------------
// GEMM: P[ks][m][n] = A(K-half ks) @ B-columns [n0, n0+32)
// grid (256 n-tiles, 2 k-splits), 256 threads (4 waves), wave-tile 64x32.
// Double-buffered LDS; A staged as f16 via global_load_lds (16B), B staged
// as fp32 via global_load_lds and converted to f16 at fragment-read time.
// Prefetch for phase kk+1 is issued right after the barrier, before the
// compute of phase kk, so the HBM flight overlaps compute.
// ---------------------------------------------------------------------------
__global__ __launch_bounds__(256) void gemm_kernel(
    const _Float16* __restrict__ Ahi,
    const float* __restrict__ Wz, const float* __restrict__ Wi,
    const float* __restrict__ Wf, const float* __restrict__ Wo,
    const float* __restrict__ Uz, const float* __restrict__ Ui,
    const float* __restrict__ Uf, const float* __restrict__ Uo,
    float* __restrict__ P)
{
    // A: BK=64 -> 8 chunks x 256 rows x 8 halfs = 16384 halfs = 32 KB / buf
    __shared__ __align__(16) _Float16 sA[2][8 * 256 * 8];   // 64 KB
    // B: 64 k-rows x 32 cols fp32 = 8 KB / buf
    __shared__ __align__(16) float    sB[2][BK * BN];       // 16 KB

    const int t    = threadIdx.x;
    const int w    = t >> 6;          // wave 0..3
    const int lane = t & 63;
    const int lg   = lane >> 5;
    const int lm   = lane & 31;

    const int nblk = blockIdx.x;      // 0..255
    const int ks   = blockIdx.y;      // 0..1
    const int n0   = nblk * BN;
    const int g    = n0 >> 11;        // gate 0..3
    const int c0   = n0 & (U_ - 1);

    const float* wsel[8] = {Wz, Wi, Wf, Wo, Uz, Ui, Uf, Uo};
    const float* Bm = wsel[ks * 4 + g];        // ks=0 -> W*, ks=1 -> U*
    const int chunk0 = ks * 256;               // A chunk base (chunk = k/8)

    // staging source indices (per thread)
    const int arow_t = t;                      // A: thread -> row within chunk
    const int bk_t   = t >> 3;                 // B: k-row 0..31 (x2 instrs)
    const int bc_t   = (t & 7) * 4;            // B: col chunk

    floatx16 acc[2] = {};

#define STAGE(kk, buf)                                                        \
    {                                                                         \
        int gch = chunk0 + (kk) * 8;                                          \
        _Pragma("unroll")                                                     \
        for (int i = 0; i < 8; ++i) {                                         \
            int gidx = ((gch + i) * 256 + arow_t) * 8;                        \
            int lidx = (i * 256 + arow_t) * 8;                                \
            __builtin_amdgcn_global_load_lds(                                 \
                (const __attribute__((address_space(1))) void*)(Ahi + gidx),  \
                (__attribute__((address_space(3))) void*)(&sA[buf][lidx]),    \
                16, 0, 0);                                                    \
        }                                                                     \
        _Pragma("unroll")                                                     \
        for (int j = 0; j < 2; ++j) {                                         \
            int krow = j * 32 + bk_t;                                         \
            const float* src = Bm + (size_t)((kk) * BK + krow) * U_ + c0 + bc_t; \
            __builtin_amdgcn_global_load_lds(                                 \
                (const __attribute__((address_space(1))) void*)(src),         \
                (__attribute__((address_space(3))) void*)(&sB[buf][krow * BN + bc_t]), \
                16, 0, 0);                                                    \
        }                                                                     \
    }

    STAGE(0, 0);
    __syncthreads();

    for (int kk = 0; kk < ITERS; ++kk) {
        int cur = kk & 1;
        if (kk + 1 < ITERS) STAGE(kk + 1, cur ^ 1);

        // compute phase: 4 k-instrs of 32x32x16
#pragma unroll
        for (int kin = 0; kin < 4; ++kin) {
            half8 a0, a1, bf;
            {
                int chunkIdx = kin * 2 + lg;
                int row0 = w * 64 + lm;
                a0 = *(const half8*)(&sA[cur][(chunkIdx * 256 + row0) * 8]);
                a1 = *(const half8*)(&sA[cur][(chunkIdx * 256 + row0 + 32) * 8]);
            }
#pragma unroll
            for (int j = 0; j < 8; ++j) {
                float v = sB[cur][(kin * 16 + lg * 8 + j) * BN + lm];
                bf[j] = (_Float16)v;
            }
            acc[0] = __builtin_amdgcn_mfma_f32_32x32x16_f16(a0, bf, acc[0], 0, 0, 0);
            acc[1] = __builtin_amdgcn_mfma_f32_32x32x16_f16(a1, bf, acc[1], 0, 0, 0);
        }
        __syncthreads();
    }
#undef STAGE

    // C/D layout: col=lane&31, row=(r&3)+8*(r>>2)+4*(lane>>5)
    float* Pks = P + (size_t)ks * ((size_t)B_ * NTOT);
#pragma unroll
    for (int mt = 0; mt < 2; ++mt)
#pragma unroll
        for (int r = 0; r < 16; ++r) {
            int m = w * 64 + mt * 32 + 4 * lg + (r & 3) + 8 * (r >> 2);
            Pks[(size_t)m * NTOT + n0 + lm] = acc[mt][r];
        }
}

// ---------------------------------------------------------------------------
// gates: reduce 2 partials, add bias, sLSTM exponential-gate math,
// out = stack([h_t, c_t, n_t, m_t])
// ---------------------------------------------------------------------------
__global__ __launch_bounds__(256) void gates_kernel(
    const float* __restrict__ P,
    const float* __restrict__ c_prev, const float* __restrict__ n_prev,
    const float* __restrict__ m_prev,
    const float* __restrict__ bz, const float* __restrict__ bi,
    const float* __restrict__ bf, const float* __restrict__ bo,
    float* __restrict__ out)
{
    const size_t PS = (size_t)B_ * NTOT;
    const int OS = B_ * U_;
    int gid = blockIdx.x * 256 + threadIdx.x;   // 131072
    int m = gid >> 9;
    int u = (gid & 511) * 4;

    float pre[4][4];
#pragma unroll
    for (int gi = 0; gi < 4; ++gi) {
        const float* base = P + (size_t)m * NTOT + gi * U_ + u;
        float4 s0 = *(const float4*)(base);
        float4 s1 = *(const float4*)(base + PS);
        pre[gi][0] = s0.x + s1.x;
        pre[gi][1] = s0.y + s1.y;
        pre[gi][2] = s0.z + s1.z;
        pre[gi][3] = s0.w + s1.w;
    }
    float4 bzv = *(const float4*)(bz + u);
    float4 biv = *(const float4*)(bi + u);
    float4 bfv = *(const float4*)(bf + u);
    float4 bov = *(const float4*)(bo + u);
    float bza[4] = {bzv.x, bzv.y, bzv.z, bzv.w};
    float bia[4] = {biv.x, biv.y, biv.z, biv.w};
    float bfa[4] = {bfv.x, bfv.y, bfv.z, bfv.w};
    float boa[4] = {bov.x, bov.y, bov.z, bov.w};

    float4 cp4 = *(const float4*)(c_prev + m * U_ + u);
    float4 np4 = *(const float4*)(n_prev + m * U_ + u);
    float4 mp4 = *(const float4*)(m_prev + m * U_ + u);
    float cpa[4] = {cp4.x, cp4.y, cp4.z, cp4.w};
    float npa[4] = {np4.x, np4.y, np4.z, np4.w};
    float mpa[4] = {mp4.x, mp4.y, mp4.z, mp4.w};

    float hr[4], cr[4], nr[4], mr[4];
#pragma unroll
    for (int e = 0; e < 4; ++e) {
        float zt = pre[0][e] + bza[e];
        float it = pre[1][e] + bia[e];
        float ft = pre[2][e] + bfa[e];
        float ot = pre[3][e] + boa[e];
        float mp = mpa[e];
        float m_t = fmaxf(it + mp, it);
        float i_t = expf(it - m_t);
        float f_t = expf(ft + mp - m_t);
        float o_t = 1.0f / (1.0f + expf(-ot));
        float z_t = tanhf(zt);
        float c_t = f_t * cpa[e] + i_t * z_t;
        float n_t = f_t * npa[e] + i_t;
        float h_t = o_t * (c_t / (n_t + 1e-8f));
        hr[e] = h_t; cr[e] = c_t; nr[e] = n_t; mr[e] = m_t;
    }
    float4 hv = {hr[0], hr[1], hr[2], hr[3]};
    float4 cv = {cr[0], cr[1], cr[2], cr[3]};
    float4 nv = {nr[0], nr[1], nr[2], nr[3]};
    float4 mv = {mr[0], mr[1], mr[2], mr[3]};
    *(float4*)(out + 0 * OS + m * U_ + u) = hv;
    *(float4*)(out + 1 * OS + m * U_ + u) = cv;
    *(float4*)(out + 2 * OS + m * U_ + u) = nv;
    *(float4*)(out + 3 * OS + m * U_ + u) = mv;
}

extern "C" void kernel_launch(void* const* d_in, const int* in_sizes, int n_in,
                              void* d_out, int out_size, void* d_ws, size_t ws_size,
                              hipStream_t stream)
{
    const float* x  = (const float*)d_in[0];
    const float* h  = (const float*)d_in[1];
    const float* cp = (const float*)d_in[2];
    const float* np = (const float*)d_in[3];
    const float* mp = (const float*)d_in[4];
    const float* Wz = (const float*)d_in[5];
    const float* Wi = (const float*)d_in[6];
    const float* Wf = (const float*)d_in[7];
    const float* Wo = (const float*)d_in[8];
    const float* bz = (const float*)d_in[9];
    const float* bi = (const float*)d_in[10];
    const float* bf = (const float*)d_in[11];
    const float* bo = (const float*)d_in[12];
    const float* Uz = (const float*)d_in[13];
    const float* Ui = (const float*)d_in[14];
    const float* Uf = (const float*)d_in[15];
    const float* Uo = (const float*)d_in[16];

    float* P = (float*)d_ws;                         // 2*256*8192 f32 = 16.8 MB
    _Float16* Ahi = (_Float16*)((char*)d_ws + (size_t)2 * B_ * NTOT * sizeof(float));

    prep_kernel<<<512, 256, 0, stream>>>(x, h, Ahi);
    gemm_kernel<<<dim3(256, 2), 256, 0, stream>>>(Ahi,
        Wz, Wi, Wf, Wo, Uz, Ui, Uf, Uo, P);
    gates_kernel<<<512, 256, 0, stream>>>(P, cp, np, mp, bz, bi, bf, bo,
        (float*)d_out);
}